// Round 4
// baseline (154.536 us; speedup 1.0000x reference)
//
#include <hip/hip_runtime.h>
#include <hip/hip_bf16.h>
#include <hip/hip_cooperative_groups.h>
#include <math.h>

namespace cg = cooperative_groups;

#define B_DIM 16
#define T_DIM 100
#define TPAD 112            // X16 rows per batch (12 zeroed pad rows)
#define HW_PIX (27 * 48)    // 1296 pixels/frame
#define NBINS 512
#define WIN 101
#define HALF 50
#define ODIM 128
#define NCHUNK 7            // t-chunks of 16 per batch
#define SSTR 132            // slds col stride (128 + 4 pad)
#define NUNITS (B_DIM * T_DIM + B_DIM * (TPAD - T_DIM))  // 1792
#define GRID_BLOCKS 448     // 448*4 = 1792 units; <=512 co-residency at 60KB LDS

typedef __attribute__((ext_vector_type(8))) short s16x8;
typedef __attribute__((ext_vector_type(4))) float f32x4;

// ---------------------------------------------------------------------------
// Single cooperative kernel.
// Phase 1 (all 448 blocks): 4 histogram-units each -> X16[b][tpad][512] bf16,
//   L2-normalized, pad rows 100..111 zeroed.
// grid.sync()
// Phase 2 (blocks 0..111): 16x128 sim strip via MFMA into LDS, then
//   band extraction + FC(101->128) + ReLU.
// LDS: phase1 uses first 2KB+ as h[512]/red; phase2 reuses as wlds+slds.
// ---------------------------------------------------------------------------
__global__ __launch_bounds__(256) void fused_kernel(
    const int* __restrict__ frames, const float* __restrict__ fc_w,
    const float* __restrict__ fc_b, float* __restrict__ out,
    __hip_bfloat16* __restrict__ X16) {
  __shared__ __align__(16) char smem[WIN * ODIM * 4 + 16 * SSTR * 4];  // 60160 B

  const int tid = threadIdx.x;
  const int lane = tid & 63, w = tid >> 6;

  // ---------------- phase 1: histograms ----------------
  {
    int* h = (int*)smem;
    float* red = (float*)(smem + NBINS * 4);

#pragma unroll 1
    for (int i = 0; i < 4; ++i) {
      const int u = blockIdx.x * 4 + i;   // 0..1791, block-uniform branch below
      if (u >= B_DIM * T_DIM) {
        // zero one pad row
        const int pid = u - B_DIM * T_DIM;          // 0..191
        const int b = pid / (TPAD - T_DIM);
        const int r = pid - b * (TPAD - T_DIM);
        unsigned int* row = (unsigned int*)(X16 + ((size_t)(b * TPAD + T_DIM + r)) * NBINS);
        row[tid] = 0u;                               // 256 uints = 512 bf16
        continue;
      }

      for (int k = tid; k < NBINS; k += 256) h[k] = 0;
      __syncthreads();

      // 1296 pixels = 324 groups of 4 pixels (12 dwords = 3 int4 loads)
      const int* fp = frames + (size_t)u * (HW_PIX * 3);
      for (int g = tid; g < HW_PIX / 4; g += 256) {
        const int4* q = (const int4*)(fp + 12 * g);
        int4 a = q[0], c = q[1], e = q[2];
        int b0 = ((a.x >> 5) << 6) + ((a.y >> 5) << 3) + (a.z >> 5);
        int b1 = ((a.w >> 5) << 6) + ((c.x >> 5) << 3) + (c.y >> 5);
        int b2 = ((c.z >> 5) << 6) + ((c.w >> 5) << 3) + (e.x >> 5);
        int b3 = ((e.y >> 5) << 6) + ((e.z >> 5) << 3) + (e.w >> 5);
        atomicAdd(&h[b0], 1);
        atomicAdd(&h[b1], 1);
        atomicAdd(&h[b2], 1);
        atomicAdd(&h[b3], 1);
      }
      __syncthreads();

      float ss = 0.f;
      for (int k = tid; k < NBINS; k += 256) {
        float v = (float)h[k];
        ss += v * v;
      }
#pragma unroll
      for (int off = 32; off > 0; off >>= 1) ss += __shfl_down(ss, off);
      if (lane == 0) red[w] = ss;
      __syncthreads();
      if (tid == 0) red[8] = 1.0f / sqrtf(red[0] + red[1] + red[2] + red[3]);
      __syncthreads();
      const float rn = red[8];

      const int b = u / T_DIM;
      const int t = u - b * T_DIM;
      __hip_bfloat16* row = X16 + ((size_t)(b * TPAD + t)) * NBINS;
      // packed bf16x2 stores: thread tid owns bins 2*tid, 2*tid+1
      __hip_bfloat162 v2;
      v2.x = __float2bfloat16((float)h[2 * tid] * rn);
      v2.y = __float2bfloat16((float)h[2 * tid + 1] * rn);
      ((__hip_bfloat162*)row)[tid] = v2;
      __syncthreads();   // h reused next iteration
    }
  }

  cg::this_grid().sync();

  // ---------------- phase 2: sim strip + band + FC ----------------
  if (blockIdx.x >= B_DIM * NCHUNK) return;

  float* wlds = (float*)smem;                        // 101*128 f32
  float* slds = (float*)(smem + WIN * ODIM * 4);     // 16*SSTR f32

  const int cid = blockIdx.x;
  const int b = cid / NCHUNK;
  const int t0 = (cid - b * NCHUNK) * 16;
  const int s0 = t0 - HALF;
  const int m16 = lane & 15, quad = lane >> 4;

  // stage fc_w as float4
  {
    const f32x4* src = (const f32x4*)fc_w;
    f32x4* dst = (f32x4*)wlds;
    for (int i = tid; i < (WIN * ODIM) / 4; i += 256) dst[i] = src[i];
  }

  // MFMA: 8 col-tiles (s = s0 + 16c + n), 2 per wave
  {
    const int c0 = 2 * w;
    const short* A = (const short*)(X16 + ((size_t)(b * TPAD + t0 + m16)) * NBINS) + quad * 8;
    int sa = s0 + c0 * 16 + m16;
    int sb = sa + 16;
    sa = min(max(sa, 0), TPAD - 1);   // clamped rows land in zero padding or are
    sb = min(max(sb, 0), TPAD - 1);   // masked by the jlo/jhi window below
    const short* B0 = (const short*)(X16 + ((size_t)(b * TPAD + sa)) * NBINS) + quad * 8;
    const short* B1 = (const short*)(X16 + ((size_t)(b * TPAD + sb)) * NBINS) + quad * 8;

    f32x4 acc0 = {0.f, 0.f, 0.f, 0.f};
    f32x4 acc1 = {0.f, 0.f, 0.f, 0.f};
#pragma unroll 4
    for (int k = 0; k < NBINS; k += 32) {
      s16x8 af = *(const s16x8*)(A + k);
      acc0 = __builtin_amdgcn_mfma_f32_16x16x32_bf16(af, *(const s16x8*)(B0 + k), acc0, 0, 0, 0);
      acc1 = __builtin_amdgcn_mfma_f32_16x16x32_bf16(af, *(const s16x8*)(B1 + k), acc1, 0, 0, 0);
    }
#pragma unroll
    for (int r = 0; r < 4; ++r) {
      slds[(quad * 4 + r) * SSTR + c0 * 16 + m16] = acc0[r];
      slds[(quad * 4 + r) * SSTR + (c0 + 1) * 16 + m16] = acc1[r];
    }
  }
  __syncthreads();

  // band + FC: thread owns d-quad g4 and rows tl0, tl0+8
  const int g4 = tid & 31;
  const int tl0 = tid >> 5;
  const int tl1 = tl0 + 8;
  const int t_a = t0 + tl0, t_b = t0 + tl1;
  const int jlo0 = max(0, HALF - t_a), jhi0 = min(WIN, HALF + T_DIM - t_a);
  const int jlo1 = max(0, HALF - t_b), jhi1 = min(WIN, HALF + T_DIM - t_b);

  f32x4 acc0 = ((const f32x4*)fc_b)[g4];
  f32x4 acc1 = acc0;
#pragma unroll 4
  for (int j = 0; j < WIN; ++j) {
    f32x4 wv = *(const f32x4*)&wlds[j * ODIM + g4 * 4];
    float b0 = (j >= jlo0 && j < jhi0) ? slds[tl0 * SSTR + tl0 + j] : 0.f;
    float b1 = (j >= jlo1 && j < jhi1) ? slds[tl1 * SSTR + tl1 + j] : 0.f;
    acc0 += wv * b0;
    acc1 += wv * b1;
  }

#pragma unroll
  for (int c = 0; c < 4; ++c) {
    acc0[c] = fmaxf(acc0[c], 0.f);
    acc1[c] = fmaxf(acc1[c], 0.f);
  }

  if (t_a < T_DIM)
    *(f32x4*)&out[(((size_t)b * T_DIM + t_a)) * ODIM + g4 * 4] = acc0;
  if (t_b < T_DIM)
    *(f32x4*)&out[(((size_t)b * T_DIM + t_b)) * ODIM + g4 * 4] = acc1;
}

extern "C" void kernel_launch(void* const* d_in, const int* in_sizes, int n_in,
                              void* d_out, int out_size, void* d_ws, size_t ws_size,
                              hipStream_t stream) {
  const int* frames = (const int*)d_in[0];     // (16,100,27,48,3) int32
  const float* fc_w = (const float*)d_in[1];   // (101,128) f32
  const float* fc_b = (const float*)d_in[2];   // (128,) f32
  float* out = (float*)d_out;                  // (16,100,128) f32
  __hip_bfloat16* X16 = (__hip_bfloat16*)d_ws; // 16*112*512 bf16 = 1.835 MB

  void* args[] = {(void*)&frames, (void*)&fc_w, (void*)&fc_b, (void*)&out, (void*)&X16};
  hipLaunchCooperativeKernel((const void*)fused_kernel, dim3(GRID_BLOCKS), dim3(256),
                             args, 0, stream);
}

// Round 5
// 88.659 us; speedup vs baseline: 1.7430x; 1.7430x over previous
//
#include <hip/hip_runtime.h>
#include <hip/hip_bf16.h>
#include <math.h>

#define B_DIM 16
#define T_DIM 100
#define TPAD 112            // 7 MFMA row-tiles of 16
#define HW_PIX (27 * 48)    // 1296 pixels/frame
#define NBINS 512
#define WIN 101
#define HALF 50
#define ODIM 128
#define NTILE 7             // TPAD/16
#define BSTRIDE 104         // band row stride in LDS (bank-offset 8/row)

typedef __attribute__((ext_vector_type(8))) short s16x8;
typedef __attribute__((ext_vector_type(4))) float f32x4;

// ---------------------------------------------------------------------------
// Kernel A: per-frame 512-bin histogram, L2-normalized, stored bf16 into
// X16[b][t][512] with rows 100..111 zeroed (MFMA padding).
// blocks 0..1599: one frame each. blocks 1600..1791: zero one pad row each.
// ---------------------------------------------------------------------------
__global__ __launch_bounds__(256) void hist_kernel(
    const int* __restrict__ frames, __hip_bfloat16* __restrict__ X16) {
  const int bid = blockIdx.x;
  const int tid = threadIdx.x;

  if (bid >= B_DIM * T_DIM) {
    // zero a pad row: rows (b*112 + 100..111)
    const int pid = bid - B_DIM * T_DIM;      // 0..191
    const int b = pid / (TPAD - T_DIM);
    const int r = pid - b * (TPAD - T_DIM);
    unsigned int* row = (unsigned int*)(X16 + ((size_t)(b * TPAD + T_DIM + r)) * NBINS);
    row[tid] = 0u;                             // 256 uints = 512 bf16
    return;
  }

  __shared__ int h[NBINS];
  __shared__ float red[16];

  for (int i = tid; i < NBINS; i += 256) h[i] = 0;
  __syncthreads();

  // 1296 pixels = 324 groups of 4 pixels (12 dwords = 3 int4 loads)
  const int* fp = frames + (size_t)bid * (HW_PIX * 3);
  for (int i = tid; i < HW_PIX / 4; i += 256) {
    const int4* q = (const int4*)(fp + 12 * i);
    int4 a = q[0], c = q[1], e = q[2];
    int b0 = ((a.x >> 5) << 6) + ((a.y >> 5) << 3) + (a.z >> 5);
    int b1 = ((a.w >> 5) << 6) + ((c.x >> 5) << 3) + (c.y >> 5);
    int b2 = ((c.z >> 5) << 6) + ((c.w >> 5) << 3) + (e.x >> 5);
    int b3 = ((e.y >> 5) << 6) + ((e.z >> 5) << 3) + (e.w >> 5);
    atomicAdd(&h[b0], 1);
    atomicAdd(&h[b1], 1);
    atomicAdd(&h[b2], 1);
    atomicAdd(&h[b3], 1);
  }
  __syncthreads();

  float ss = 0.f;
  for (int i = tid; i < NBINS; i += 256) {
    float v = (float)h[i];
    ss += v * v;
  }
  const int lane = tid & 63, wave = tid >> 6;
#pragma unroll
  for (int off = 32; off > 0; off >>= 1) ss += __shfl_down(ss, off);
  if (lane == 0) red[wave] = ss;
  __syncthreads();
  if (tid == 0) red[8] = 1.0f / sqrtf(red[0] + red[1] + red[2] + red[3]);
  __syncthreads();
  const float rn = red[8];

  const int b = bid / T_DIM;
  const int t = bid - b * T_DIM;
  __hip_bfloat16* row = X16 + ((size_t)(b * TPAD + t)) * NBINS;
  // packed bf16x2 store: thread tid owns bins 2*tid, 2*tid+1
  __hip_bfloat162 v2;
  v2.x = __float2bfloat16((float)h[2 * tid] * rn);
  v2.y = __float2bfloat16((float)h[2 * tid + 1] * rn);
  ((__hip_bfloat162*)row)[tid] = v2;
}

// ---------------------------------------------------------------------------
// Kernel B: sim[b] = X[b] · X[b]^T via MFMA bf16 16x16x32.
// One wave per 16x16 output tile; grid = 16 batches * 49 tiles.
//   A frag: A[m=lane&15][k=quad*8+j]; B frag: B[n=lane&15][k=quad*8+j]
//   D frag: col=lane&15, row=quad*4+reg
// ---------------------------------------------------------------------------
__global__ __launch_bounds__(64) void sim_kernel(
    const __hip_bfloat16* __restrict__ X16, float* __restrict__ sim) {
  const int bid = blockIdx.x;
  const int b = bid / (NTILE * NTILE);
  const int tile = bid - b * (NTILE * NTILE);
  const int tm = tile / NTILE, tn = tile - tm * NTILE;
  const int lane = threadIdx.x;
  const int m16 = lane & 15, quad = lane >> 4;

  const short* A = (const short*)(X16 + ((size_t)(b * TPAD + tm * 16 + m16)) * NBINS) + quad * 8;
  const short* Bp = (const short*)(X16 + ((size_t)(b * TPAD + tn * 16 + m16)) * NBINS) + quad * 8;

  f32x4 acc = {0.f, 0.f, 0.f, 0.f};
#pragma unroll 4
  for (int k = 0; k < NBINS; k += 32) {
    s16x8 af = *(const s16x8*)(A + k);
    s16x8 bf = *(const s16x8*)(Bp + k);
    acc = __builtin_amdgcn_mfma_f32_16x16x32_bf16(af, bf, acc, 0, 0, 0);
  }

  const int n = tn * 16 + m16;
  if (n < T_DIM) {
    float* srow = sim + (size_t)b * T_DIM * T_DIM + n;
#pragma unroll
    for (int r = 0; r < 4; ++r) {
      int m = tm * 16 + quad * 4 + r;
      if (m < T_DIM) srow[(size_t)m * T_DIM] = acc[r];
    }
  }
}

// ---------------------------------------------------------------------------
// Kernel C: band extraction + FC(101->128) + ReLU.
// Grid = 16 batches * 7 chunks of 16 t's; 256 threads.
// LDS: fc_w (101x128 f32) + band (16 x BSTRIDE f32).
// Thread owns d-quad (g4 = tid&31 -> d=4*g4..) and tl in {tid>>5, (tid>>5)+8}.
// ---------------------------------------------------------------------------
__global__ __launch_bounds__(256) void band_fc_kernel(
    const float* __restrict__ sim, const float* __restrict__ fc_w,
    const float* __restrict__ fc_b, float* __restrict__ out) {
  __shared__ __align__(16) float wlds[WIN * ODIM];   // 51712 B
  __shared__ float blds[16 * BSTRIDE];               // 6656 B

  const int cid = blockIdx.x;
  const int b = cid / NTILE;
  const int t0 = (cid - b * NTILE) * 16;
  const int tid = threadIdx.x;

  // stage fc_w as float4
  {
    const f32x4* src = (const f32x4*)fc_w;
    f32x4* dst = (f32x4*)wlds;
    for (int i = tid; i < (WIN * ODIM) / 4; i += 256) dst[i] = src[i];
  }
  // stage band rows (zero outside valid range)
  for (int idx = tid; idx < 16 * WIN; idx += 256) {
    int tl = idx / WIN;
    int j = idx - tl * WIN;
    int t = t0 + tl;
    int s = t - HALF + j;
    float v = 0.f;
    if (t < T_DIM && s >= 0 && s < T_DIM)
      v = sim[((size_t)b * T_DIM + t) * T_DIM + s];
    blds[tl * BSTRIDE + j] = v;
  }
  __syncthreads();

  const int g4 = tid & 31;        // d = 4*g4 .. 4*g4+3
  const int tl0 = tid >> 5;       // 0..7
  const int tl1 = tl0 + 8;

  f32x4 acc0 = ((const f32x4*)fc_b)[g4];
  f32x4 acc1 = acc0;
#pragma unroll 4
  for (int j = 0; j < WIN; ++j) {
    f32x4 wv = *(const f32x4*)&wlds[j * ODIM + g4 * 4];
    float b0 = blds[tl0 * BSTRIDE + j];
    float b1 = blds[tl1 * BSTRIDE + j];
    acc0 += wv * b0;
    acc1 += wv * b1;
  }

#pragma unroll
  for (int c = 0; c < 4; ++c) {
    acc0[c] = fmaxf(acc0[c], 0.f);
    acc1[c] = fmaxf(acc1[c], 0.f);
  }

  const int t0a = t0 + tl0, t0b = t0 + tl1;
  if (t0a < T_DIM)
    *(f32x4*)&out[(((size_t)b * T_DIM + t0a)) * ODIM + g4 * 4] = acc0;
  if (t0b < T_DIM)
    *(f32x4*)&out[(((size_t)b * T_DIM + t0b)) * ODIM + g4 * 4] = acc1;
}

extern "C" void kernel_launch(void* const* d_in, const int* in_sizes, int n_in,
                              void* d_out, int out_size, void* d_ws, size_t ws_size,
                              hipStream_t stream) {
  const int* frames = (const int*)d_in[0];     // (16,100,27,48,3) int32
  const float* fc_w = (const float*)d_in[1];   // (101,128) f32
  const float* fc_b = (const float*)d_in[2];   // (128,) f32
  float* out = (float*)d_out;                  // (16,100,128) f32

  __hip_bfloat16* X16 = (__hip_bfloat16*)d_ws;                    // 16*112*512 bf16 = 1.835 MB
  float* sim = (float*)((char*)d_ws + (size_t)B_DIM * TPAD * NBINS * 2);  // 16*100*100 f32

  hist_kernel<<<B_DIM * T_DIM + B_DIM * (TPAD - T_DIM), 256, 0, stream>>>(frames, X16);
  sim_kernel<<<B_DIM * NTILE * NTILE, 64, 0, stream>>>(X16, sim);
  band_fc_kernel<<<B_DIM * NTILE, 256, 0, stream>>>(sim, fc_w, fc_b, out);
}